// Round 3
// baseline (1493.279 us; speedup 1.0000x reference)
//
#include <hip/hip_runtime.h>
#include <hip/hip_bf16.h>

#define NN 50000
#define NE 800000
#define NB 16
#define T_STEPS 12
#define SCAN_B 196  // ceil(NN/256)

typedef __attribute__((ext_vector_type(8))) short short8;
typedef __attribute__((ext_vector_type(4))) float f32x4;
typedef __attribute__((ext_vector_type(2))) float f32x2;
typedef unsigned short u16;
typedef unsigned int u32;

__device__ __forceinline__ float bf2f(u32 u) {
    union { u32 i; float f; } v; v.i = u << 16; return v.f;
}
__device__ __forceinline__ u16 f2bf(float f) {
    union { float f; u32 i; } v; v.f = f;
    u32 r = v.i + 0x7fffu + ((v.i >> 16) & 1u);
    return (u16)(r >> 16);
}
__device__ __forceinline__ f32x4 mfma16(short8 a, short8 b, f32x4 c) {
    return __builtin_amdgcn_mfma_f32_16x16x32_bf16(a, b, c, 0, 0, 0);
}

// OCP e4m3fn encode (manual, RTNE; setup path only)
__device__ __forceinline__ u32 f2fp8(float f) {
    float a = fabsf(f);
    u32 sign = (f < 0.f) ? 0x80u : 0u;
    if (!(a < 448.f)) return sign | 0x7eu;
    if (a < 0.015625f) {
        int q = (int)(a * 512.f + 0.5f);
        return sign | (u32)q;
    }
    union { float f; u32 i; } v; v.f = a;
    int e32 = (int)(v.i >> 23) - 127;
    u32 q = (u32)((e32 + 7) << 3) | ((v.i >> 20) & 7u);
    u32 rest = v.i & 0xfffffu;
    if (rest > 0x80000u || (rest == 0x80000u && (q & 1u))) q++;
    if (q > 0x7eu) q = 0x7eu;
    return sign | q;
}

// decode 2x fp8 (low 16 bits of w) -> 2 floats; hot path
__device__ __forceinline__ void fp8x2f(u32 w, float& f0, float& f1) {
#if __has_builtin(__builtin_amdgcn_cvt_pk_f32_fp8)
    f32x2 r = __builtin_amdgcn_cvt_pk_f32_fp8((int)w, false);
    f0 = r[0]; f1 = r[1];
#else
    u32 b0 = w & 0xffu, b1 = (w >> 8) & 0xffu;
    u32 e0 = (b0 >> 3) & 15u, m0 = b0 & 7u;
    u32 e1 = (b1 >> 3) & 15u, m1 = b1 & 7u;
    float g0 = (e0 == 0) ? (float)m0 * 0.001953125f
                         : __uint_as_float(((e0 + 120u) << 23) | (m0 << 20));
    float g1 = (e1 == 0) ? (float)m1 * 0.001953125f
                         : __uint_as_float(((e1 + 120u) << 23) | (m1 << 20));
    f0 = (b0 & 0x80u) ? -g0 : g0;
    f1 = (b1 & 0x80u) ? -g1 : g1;
#endif
}

// packed weight layout (bf16): elem(((ks*8+nt)*64+l)*8+j) = W[ks*32+((l>>4))*8+j][nt*16+(l&15)]
#define W1OFF 0
#define W2OFF 32768
#define WSOFF 49152
#define ENCOFF 65536
#define PACKN 73728

// ---------------- setup kernels ----------------

__global__ void k_hist(const int* __restrict__ dst, int* __restrict__ hist) {
    int e = blockIdx.x * 256 + threadIdx.x;
    if (e < NE) atomicAdd(&hist[dst[e]], 1);
}

// hierarchical scan: A) per-block exclusive + block sums, B) scan block sums, C) add offsets
__global__ void k_scanA(const int* __restrict__ hist, int* __restrict__ excl,
                        int* __restrict__ bsum) {
    __shared__ int sh[256];
    int t = threadIdx.x, b = blockIdx.x;
    int idx = b * 256 + t;
    int v = (idx < NN) ? hist[idx] : 0;
    sh[t] = v;
    __syncthreads();
    for (int off = 1; off < 256; off <<= 1) {
        int add = (t >= off) ? sh[t - off] : 0;
        __syncthreads();
        sh[t] += add;
        __syncthreads();
    }
    if (idx < NN) excl[idx] = sh[t] - v;
    if (t == 255) bsum[b] = sh[255];
}

__global__ void k_scanB(int* __restrict__ bsum) {
    __shared__ int sh[256];
    int t = threadIdx.x;
    int v = (t < SCAN_B) ? bsum[t] : 0;
    sh[t] = v;
    __syncthreads();
    for (int off = 1; off < 256; off <<= 1) {
        int add = (t >= off) ? sh[t - off] : 0;
        __syncthreads();
        sh[t] += add;
        __syncthreads();
    }
    if (t < SCAN_B) bsum[t] = sh[t] - v;  // exclusive
}

__global__ void k_scanC(const int* __restrict__ excl, const int* __restrict__ bsum,
                        int* __restrict__ rowptr, int* __restrict__ cursor) {
    int idx = blockIdx.x * 256 + threadIdx.x;
    if (idx < NN) {
        int r = excl[idx] + bsum[blockIdx.x];
        rowptr[idx] = r;
        cursor[idx] = r;
    }
    if (idx == 0) rowptr[NN] = NE;
}

__global__ void k_scatter(const int* __restrict__ src, const int* __restrict__ dst,
                          const float* __restrict__ eattr, int* __restrict__ cursor,
                          int* __restrict__ ssrc, u16* __restrict__ ea8) {
    int e = blockIdx.x * 256 + threadIdx.x;
    if (e >= NE) return;
    int d = dst[e];
    int pos = atomicAdd(&cursor[d], 1);
    ssrc[pos] = src[e];
    const float* ap = eattr + (size_t)e * 8;
    uint4 w;
    w.x = (u32)f2bf(ap[0]) | ((u32)f2bf(ap[1]) << 16);
    w.y = (u32)f2bf(ap[2]) | ((u32)f2bf(ap[3]) << 16);
    w.z = (u32)f2bf(ap[4]) | ((u32)f2bf(ap[5]) << 16);
    w.w = (u32)f2bf(ap[6]) | ((u32)f2bf(ap[7]) << 16);
    *(uint4*)(ea8 + (size_t)pos * 8) = w;
}

// eaw[i][c] = fp8( sum_k ea8[i][k] * msg_w[128+k][c] )  (CSR-sorted edge order)
__global__ __launch_bounds__(256) void k_eaw(
    const u16* __restrict__ ea8, const float* __restrict__ msg_w,
    unsigned char* __restrict__ eaw) {
    __shared__ float wlds[8][128];
    int t = threadIdx.x;
    for (int i = t; i < 1024; i += 256) {
        int k = i >> 7, c = i & 127;
        wlds[k][c] = msg_w[(size_t)(128 + k) * 128 + c];
    }
    __syncthreads();
    int e = blockIdx.x * 8 + (t >> 5);
    if (e >= NE) return;
    int w = t & 31;  // channels 4w..4w+3
    uint4 ev = *(const uint4*)(ea8 + (size_t)e * 8);
    float ef[8];
    ef[0] = bf2f(ev.x & 0xffffu); ef[1] = bf2f(ev.x >> 16);
    ef[2] = bf2f(ev.y & 0xffffu); ef[3] = bf2f(ev.y >> 16);
    ef[4] = bf2f(ev.z & 0xffffu); ef[5] = bf2f(ev.z >> 16);
    ef[6] = bf2f(ev.w & 0xffffu); ef[7] = bf2f(ev.w >> 16);
    float o0 = 0.f, o1 = 0.f, o2 = 0.f, o3 = 0.f;
#pragma unroll
    for (int k = 0; k < 8; ++k) {
        float a = ef[k];
        o0 += a * wlds[k][4 * w + 0];
        o1 += a * wlds[k][4 * w + 1];
        o2 += a * wlds[k][4 * w + 2];
        o3 += a * wlds[k][4 * w + 3];
    }
    u32 q = f2fp8(o0) | (f2fp8(o1) << 8) | (f2fp8(o2) << 16) | (f2fp8(o3) << 24);
    *(u32*)(eaw + (size_t)e * 128 + 4 * w) = q;
}

__global__ void k_pack(const float* __restrict__ up_w1, const float* __restrict__ up_w2,
                       const float* __restrict__ msg_w, const float* __restrict__ enc_w,
                       u16* __restrict__ packed) {
    int idx = blockIdx.x * 256 + threadIdx.x;
    if (idx >= PACKN) return;
    const float* srcp; int local;
    if (idx < W2OFF)        { srcp = up_w1; local = idx; }
    else if (idx < WSOFF)   { srcp = up_w2; local = idx - W2OFF; }
    else if (idx < ENCOFF)  { srcp = msg_w; local = idx - WSOFF; }   // rows 0..127 (state part)
    else                    { srcp = enc_w; local = idx - ENCOFF; }
    int j = local & 7;
    int l = (local >> 3) & 63;
    int ntks = local >> 9;
    int nt = ntks & 7;
    int ks = ntks >> 3;
    int krow = ks * 32 + (l >> 4) * 8 + j;
    int col = nt * 16 + (l & 15);
    packed[idx] = f2bf(srcp[krow * 128 + col]);
}

// ---------------- encoder: state = relu(x@enc_w+enc_b); SW = state@Ws + msg_b ----------------

__global__ __launch_bounds__(256) void k_encode(
    const float* __restrict__ x, const float* __restrict__ enc_b,
    const float* __restrict__ msg_b, const u16* __restrict__ packed,
    float* __restrict__ state_f, u16* __restrict__ state_h, u16* __restrict__ swb) {
    __shared__ u16 stage[4][2048];
    const int wv = threadIdx.x >> 6, l = threadIdx.x & 63;
    const int lr = l & 15, kb = l >> 4;
    const int rb = blockIdx.x * 64 + wv * 16;
    const int row = rb + lr;
    const int rowc = row < NN ? row : NN - 1;

    f32x4 acc[8] = {};
#pragma unroll
    for (int ks = 0; ks < 2; ++ks) {
        const float* ap = x + (size_t)rowc * 64 + ks * 32 + kb * 8;
        float4 a0 = *(const float4*)ap;
        float4 a1 = *(const float4*)(ap + 4);
        short8 a;
        a[0] = (short)f2bf(a0.x); a[1] = (short)f2bf(a0.y);
        a[2] = (short)f2bf(a0.z); a[3] = (short)f2bf(a0.w);
        a[4] = (short)f2bf(a1.x); a[5] = (short)f2bf(a1.y);
        a[6] = (short)f2bf(a1.z); a[7] = (short)f2bf(a1.w);
        const u16* bp = packed + ENCOFF + (size_t)(ks * 512 + l) * 8;
#pragma unroll
        for (int nt = 0; nt < 8; ++nt) {
            short8 b = *(const short8*)(bp + nt * 512);
            acc[nt] = mfma16(a, b, acc[nt]);
        }
    }
#pragma unroll
    for (int nt = 0; nt < 8; ++nt) {
        int col = nt * 16 + lr;
        float bias = enc_b[col];
#pragma unroll
        for (int j = 0; j < 4; ++j) {
            int rl = kb * 4 + j;
            int r = rb + rl;
            float v = acc[nt][j] + bias;
            v = v > 0.f ? v : 0.f;
            u16 h = f2bf(v);
            if (r < NN) {
                state_f[(size_t)r * 128 + col] = v;
                state_h[(size_t)r * 128 + col] = h;
            }
            int byte = (rl * 256 + col * 2) ^ ((rl & 7) << 4);
            *(u16*)((char*)stage[wv] + byte) = h;
        }
    }
    f32x4 acc3[8] = {};
#pragma unroll
    for (int ks = 0; ks < 4; ++ks) {
        int byte = (lr * 256 + ks * 64 + kb * 16) ^ ((lr & 7) << 4);
        short8 a = *(const short8*)((char*)stage[wv] + byte);
        const u16* bp = packed + WSOFF + (size_t)(ks * 512 + l) * 8;
#pragma unroll
        for (int nt = 0; nt < 8; ++nt) {
            short8 b = *(const short8*)(bp + nt * 512);
            acc3[nt] = mfma16(a, b, acc3[nt]);
        }
    }
#pragma unroll
    for (int nt = 0; nt < 8; ++nt) {
        int col = nt * 16 + lr;
        float bias = msg_b[col];
#pragma unroll
        for (int j = 0; j < 4; ++j) {
            int r = rb + kb * 4 + j;
            if (r < NN) swb[(size_t)r * 128 + col] = f2bf(acc3[nt][j] + bias);
        }
    }
}

// ---------------- edge kernel: agg[n] = mean_e relu(SW[src_e] + EAW[e]) ----------------

__global__ __launch_bounds__(256) void k_edge(
    const int* __restrict__ rowptr, const int* __restrict__ ssrc,
    const unsigned char* __restrict__ eaw, const u16* __restrict__ swb,
    u16* __restrict__ aggb) {
    const int wv = threadIdx.x >> 6, l = threadIdx.x & 63;
    const int n = blockIdx.x * 4 + wv;
    if (n >= NN) return;
    const int e0 = rowptr[n], e1 = rowptr[n + 1];
    float a0 = 0.f, a1 = 0.f;
#pragma unroll 8
    for (int i = e0; i < e1; ++i) {
        int s = ssrc[i];
        u32 q = (u32)*(const u16*)(eaw + (size_t)i * 128 + 2 * l);
        u32 swp = *(const u32*)(swb + (size_t)s * 128 + 2 * l);
        float ex, ey;
        fp8x2f(q, ex, ey);
        union { u32 i; float f; } lo, hi;
        lo.i = swp << 16;
        hi.i = swp & 0xffff0000u;
        float m0 = lo.f + ex, m1 = hi.f + ey;
        a0 += m0 > 0.f ? m0 : 0.f;
        a1 += m1 > 0.f ? m1 : 0.f;
    }
    int dg = e1 - e0;
    float inv = 1.f / (float)(dg > 0 ? dg : 1);
    u32 outw = (u32)f2bf(a0 * inv) | ((u32)f2bf(a1 * inv) << 16);
    *(u32*)(aggb + (size_t)n * 128 + 2 * l) = outw;
}

// ---------------- update kernel: block-shared B via LDS; 128 rows/block (R=2 per wave) ----------------
// h=relu([state,agg]@W1+b1); state+=h@W2+b2; SW=state@Ws+msg_b

__global__ __launch_bounds__(256) void k_update(
    const float* __restrict__ up_b1, const float* __restrict__ up_b2,
    const float* __restrict__ msg_b, const u16* __restrict__ packed,
    const u16* __restrict__ aggb, float* __restrict__ state_f,
    u16* __restrict__ state_h, u16* __restrict__ swb) {
    __shared__ u16 bshare[16384];       // 32 KB: one 4-ks-slice chunk of packed B
    __shared__ u16 stage[4][2][2048];   // 32 KB: per-wave row-major 16x128 staging
    const int tid = threadIdx.x;
    const int wv = tid >> 6, l = tid & 63;
    const int lr = l & 15, kb = l >> 4;
    const int rbase = blockIdx.x * 128 + wv * 32;

    // prefetch all GEMM1 A-fragments (overlaps with first B staging)
    short8 aA[8][2];
#pragma unroll
    for (int ks = 0; ks < 8; ++ks) {
#pragma unroll
        for (int rt = 0; rt < 2; ++rt) {
            int row = rbase + rt * 16 + lr;
            int rowc = row < NN ? row : NN - 1;
            const u16* abase = (ks < 4)
                ? (state_h + (size_t)rowc * 128 + ks * 32 + kb * 8)
                : (aggb + (size_t)rowc * 128 + (ks - 4) * 32 + kb * 8);
            aA[ks][rt] = *(const short8*)abase;
        }
    }

    // ---- GEMM1: K=256 (W1), 2 chunks of 4 ks-slices ----
    f32x4 acc[2][8] = {};
#pragma unroll
    for (int ch = 0; ch < 2; ++ch) {
        __syncthreads();  // prior chunk's mfma reads done (no-op cost on first pass)
        const short8* gsrc = (const short8*)(packed + W1OFF + ch * 16384);
#pragma unroll
        for (int i = 0; i < 8; ++i)
            ((short8*)bshare)[tid + i * 256] = gsrc[tid + i * 256];
        __syncthreads();
#pragma unroll
        for (int k4 = 0; k4 < 4; ++k4) {
            int ks = ch * 4 + k4;
            const u16* bp = bshare + (size_t)(k4 * 512 + l) * 8;
#pragma unroll
            for (int nt = 0; nt < 8; ++nt) {
                short8 b = *(const short8*)(bp + nt * 512);
                acc[0][nt] = mfma16(aA[ks][0], b, acc[0][nt]);
                acc[1][nt] = mfma16(aA[ks][1], b, acc[1][nt]);
            }
        }
    }
    // h = relu(acc + b1) -> stage (wave-local, in-order vs our later reads)
#pragma unroll
    for (int nt = 0; nt < 8; ++nt) {
        int col = nt * 16 + lr;
        float b1v = up_b1[col];
#pragma unroll
        for (int rt = 0; rt < 2; ++rt) {
#pragma unroll
            for (int j = 0; j < 4; ++j) {
                int rl = kb * 4 + j;
                float v = acc[rt][nt][j] + b1v;
                v = v > 0.f ? v : 0.f;
                int byte = (rl * 256 + col * 2) ^ ((rl & 7) << 4);
                *(u16*)((char*)stage[wv][rt] + byte) = f2bf(v);
            }
        }
    }

    // ---- GEMM2: delta = h @ W2 (one 32 KB chunk) ----
    __syncthreads();
    {
        const short8* gsrc = (const short8*)(packed + W2OFF);
#pragma unroll
        for (int i = 0; i < 8; ++i)
            ((short8*)bshare)[tid + i * 256] = gsrc[tid + i * 256];
    }
    __syncthreads();
    f32x4 acc2[2][8] = {};
#pragma unroll
    for (int ks = 0; ks < 4; ++ks) {
        int byte = (lr * 256 + ks * 64 + kb * 16) ^ ((lr & 7) << 4);
        short8 a[2];
        a[0] = *(const short8*)((char*)stage[wv][0] + byte);
        a[1] = *(const short8*)((char*)stage[wv][1] + byte);
        const u16* bp = bshare + (size_t)(ks * 512 + l) * 8;
#pragma unroll
        for (int nt = 0; nt < 8; ++nt) {
            short8 b = *(const short8*)(bp + nt * 512);
            acc2[0][nt] = mfma16(a[0], b, acc2[0][nt]);
            acc2[1][nt] = mfma16(a[1], b, acc2[1][nt]);
        }
    }
    // state += delta + b2 ; stage <- state_new (bf16)
#pragma unroll
    for (int rt = 0; rt < 2; ++rt) {
#pragma unroll
        for (int nt = 0; nt < 8; ++nt) {
            int col = nt * 16 + lr;
            float b2v = up_b2[col];
#pragma unroll
            for (int j = 0; j < 4; ++j) {
                int rl = kb * 4 + j;
                int r = rbase + rt * 16 + rl;
                int rc = r < NN ? r : NN - 1;
                float snew = state_f[(size_t)rc * 128 + col] + acc2[rt][nt][j] + b2v;
                u16 hb = f2bf(snew);
                if (r < NN) {
                    state_f[(size_t)r * 128 + col] = snew;
                    state_h[(size_t)r * 128 + col] = hb;
                }
                int byte = (rl * 256 + col * 2) ^ ((rl & 7) << 4);
                *(u16*)((char*)stage[wv][rt] + byte) = hb;
            }
        }
    }

    // ---- GEMM3: SW = state_new @ Ws + msg_b (one 32 KB chunk) ----
    __syncthreads();
    {
        const short8* gsrc = (const short8*)(packed + WSOFF);
#pragma unroll
        for (int i = 0; i < 8; ++i)
            ((short8*)bshare)[tid + i * 256] = gsrc[tid + i * 256];
    }
    __syncthreads();
    f32x4 acc3[2][8] = {};
#pragma unroll
    for (int ks = 0; ks < 4; ++ks) {
        int byte = (lr * 256 + ks * 64 + kb * 16) ^ ((lr & 7) << 4);
        short8 a[2];
        a[0] = *(const short8*)((char*)stage[wv][0] + byte);
        a[1] = *(const short8*)((char*)stage[wv][1] + byte);
        const u16* bp = bshare + (size_t)(ks * 512 + l) * 8;
#pragma unroll
        for (int nt = 0; nt < 8; ++nt) {
            short8 b = *(const short8*)(bp + nt * 512);
            acc3[0][nt] = mfma16(a[0], b, acc3[0][nt]);
            acc3[1][nt] = mfma16(a[1], b, acc3[1][nt]);
        }
    }
#pragma unroll
    for (int rt = 0; rt < 2; ++rt) {
#pragma unroll
        for (int nt = 0; nt < 8; ++nt) {
            int col = nt * 16 + lr;
            float bias = msg_b[col];
#pragma unroll
            for (int j = 0; j < 4; ++j) {
                int r = rbase + rt * 16 + kb * 4 + j;
                if (r < NN) swb[(size_t)r * 128 + col] = f2bf(acc3[rt][nt][j] + bias);
            }
        }
    }
}

// ---------------- logits: deterministic batched segment mean over sorted batch ----------------

__global__ void k_logits(const float* __restrict__ state_f, const int* __restrict__ batch,
                         float* __restrict__ out) {
    __shared__ float red[256];
    int b = blockIdx.x, t = threadIdx.x;
    int ch = t & 7, sub = t >> 3;
    int lo = 0, hi = NN;
    while (lo < hi) { int m = (lo + hi) >> 1; if (batch[m] < b) lo = m + 1; else hi = m; }
    int s0 = lo;
    lo = 0; hi = NN;
    while (lo < hi) { int m = (lo + hi) >> 1; if (batch[m] < b + 1) lo = m + 1; else hi = m; }
    int s1 = lo;
    float acc = 0.f;
    for (int n = s0 + sub; n < s1; n += 32)
        acc += state_f[(size_t)n * 128 + 120 + ch];
    red[t] = acc;
    __syncthreads();
    for (int off = 16; off >= 1; off >>= 1) {
        if (sub < off) red[t] += red[t + off * 8];
        __syncthreads();
    }
    if (sub == 0) {
        int c = s1 - s0;
        float cnt = (float)(c > 0 ? c : 1);
        out[b * 8 + ch] = red[ch] / cnt;
    }
}

// ---------------- launch ----------------

extern "C" void kernel_launch(void* const* d_in, const int* in_sizes, int n_in,
                              void* d_out, int out_size, void* d_ws, size_t ws_size,
                              hipStream_t stream) {
    (void)in_sizes; (void)n_in;
    const float* x      = (const float*)d_in[0];
    const int*   eidx   = (const int*)d_in[1];
    const float* eattr  = (const float*)d_in[2];
    const int*   batch  = (const int*)d_in[3];
    const float* enc_w  = (const float*)d_in[4];
    const float* enc_b  = (const float*)d_in[5];
    const float* msg_w  = (const float*)d_in[6];
    const float* msg_b  = (const float*)d_in[7];
    const float* up_w1  = (const float*)d_in[8];
    const float* up_b1  = (const float*)d_in[9];
    const float* up_w2  = (const float*)d_in[10];
    const float* up_b2  = (const float*)d_in[11];
    const int* esrc = eidx;
    const int* edst = eidx + NE;

    char* p = (char*)d_ws;
    size_t off = 0;
    auto carve = [&](size_t bytes) -> char* {
        char* r = p + off;
        off += (bytes + 255) & ~(size_t)255;
        return r;
    };
    float* state_f = (float*)carve((size_t)NN * 128 * 4);
    u16* state_h   = (u16*)carve((size_t)NN * 128 * 2);
    u16* aggb      = (u16*)carve((size_t)NN * 128 * 2);
    u16* swb       = (u16*)carve((size_t)NN * 128 * 2);
    int* ssrc      = (int*)carve((size_t)NE * 4);
    u16* ea8       = (u16*)carve((size_t)NE * 8 * 2);
    unsigned char* eaw = (unsigned char*)carve((size_t)NE * 128);
    int* rowptr    = (int*)carve((size_t)(NN + 1) * 4);
    int* cursor    = (int*)carve((size_t)NN * 4);
    int* hist      = (int*)carve((size_t)NN * 4);
    int* sexcl     = (int*)carve((size_t)NN * 4);
    int* bsum      = (int*)carve((size_t)256 * 4);
    u16* packed    = (u16*)carve((size_t)PACKN * 2);
    if (off > ws_size) {
        // sentinel: NaN output tells us the workspace was too small
        hipMemsetAsync(d_out, 0xFF, (size_t)out_size * 4, stream);
        return;
    }

    hipMemsetAsync(hist, 0, (size_t)NN * 4, stream);
    k_hist<<<(NE + 255) / 256, 256, 0, stream>>>(edst, hist);
    k_scanA<<<SCAN_B, 256, 0, stream>>>(hist, sexcl, bsum);
    k_scanB<<<1, 256, 0, stream>>>(bsum);
    k_scanC<<<SCAN_B, 256, 0, stream>>>(sexcl, bsum, rowptr, cursor);
    k_scatter<<<(NE + 255) / 256, 256, 0, stream>>>(esrc, edst, eattr, cursor, ssrc, ea8);
    k_eaw<<<(NE + 7) / 8, 256, 0, stream>>>(ea8, msg_w, eaw);
    k_pack<<<(PACKN + 255) / 256, 256, 0, stream>>>(up_w1, up_w2, msg_w, enc_w, packed);
    k_encode<<<(NN + 63) / 64, 256, 0, stream>>>(x, enc_b, msg_b, packed, state_f, state_h, swb);
    for (int t = 0; t < T_STEPS; ++t) {
        k_edge<<<(NN + 3) / 4, 256, 0, stream>>>(rowptr, ssrc, eaw, swb, aggb);
        k_update<<<(NN + 127) / 128, 256, 0, stream>>>(up_b1, up_b2, msg_b, packed, aggb,
                                                       state_f, state_h, swb);
    }
    k_logits<<<NB, 256, 0, stream>>>(state_f, batch, (float*)d_out);
}

// Round 4
// 1244.109 us; speedup vs baseline: 1.2003x; 1.2003x over previous
//
#include <hip/hip_runtime.h>
#include <hip/hip_bf16.h>

#define NN 50000
#define NE 800000
#define NB 16
#define T_STEPS 12
#define SCAN_B 196  // ceil(NN/256)

typedef __attribute__((ext_vector_type(8))) short short8;
typedef __attribute__((ext_vector_type(4))) float f32x4;
typedef __attribute__((ext_vector_type(2))) float f32x2;
typedef unsigned short u16;
typedef unsigned int u32;

__device__ __forceinline__ float bf2f(u32 u) {
    union { u32 i; float f; } v; v.i = u << 16; return v.f;
}
__device__ __forceinline__ u16 f2bf(float f) {
    union { float f; u32 i; } v; v.f = f;
    u32 r = v.i + 0x7fffu + ((v.i >> 16) & 1u);
    return (u16)(r >> 16);
}
__device__ __forceinline__ f32x4 mfma16(short8 a, short8 b, f32x4 c) {
    return __builtin_amdgcn_mfma_f32_16x16x32_bf16(a, b, c, 0, 0, 0);
}

// OCP e4m3fn encode (manual fallback)
__device__ __forceinline__ u32 f2fp8(float f) {
    float a = fabsf(f);
    u32 sign = (f < 0.f) ? 0x80u : 0u;
    if (!(a < 448.f)) return sign | 0x7eu;
    if (a < 0.015625f) {
        int q = (int)(a * 512.f + 0.5f);
        return sign | (u32)q;
    }
    union { float f; u32 i; } v; v.f = a;
    int e32 = (int)(v.i >> 23) - 127;
    u32 q = (u32)((e32 + 7) << 3) | ((v.i >> 20) & 7u);
    u32 rest = v.i & 0xfffffu;
    if (rest > 0x80000u || (rest == 0x80000u && (q & 1u))) q++;
    if (q > 0x7eu) q = 0x7eu;
    return sign | q;
}

// pack 4 floats -> 4x fp8 e4m3 (HW path: 2 instructions)
__device__ __forceinline__ u32 pk4_fp8(float o0, float o1, float o2, float o3) {
#if __has_builtin(__builtin_amdgcn_cvt_pk_fp8_f32)
    int q = 0;
    q = __builtin_amdgcn_cvt_pk_fp8_f32(o0, o1, q, false);
    q = __builtin_amdgcn_cvt_pk_fp8_f32(o2, o3, q, true);
    return (u32)q;
#else
    return f2fp8(o0) | (f2fp8(o1) << 8) | (f2fp8(o2) << 16) | (f2fp8(o3) << 24);
#endif
}

// decode 2x fp8 (low 16 bits of w) -> 2 floats
__device__ __forceinline__ void fp8x2f(u32 w, float& f0, float& f1) {
#if __has_builtin(__builtin_amdgcn_cvt_pk_f32_fp8)
    f32x2 r = __builtin_amdgcn_cvt_pk_f32_fp8((int)w, false);
    f0 = r[0]; f1 = r[1];
#else
    u32 b0 = w & 0xffu, b1 = (w >> 8) & 0xffu;
    u32 e0 = (b0 >> 3) & 15u, m0 = b0 & 7u;
    u32 e1 = (b1 >> 3) & 15u, m1 = b1 & 7u;
    float g0 = (e0 == 0) ? (float)m0 * 0.001953125f
                         : __uint_as_float(((e0 + 120u) << 23) | (m0 << 20));
    float g1 = (e1 == 0) ? (float)m1 * 0.001953125f
                         : __uint_as_float(((e1 + 120u) << 23) | (m1 << 20));
    f0 = (b0 & 0x80u) ? -g0 : g0;
    f1 = (b1 & 0x80u) ? -g1 : g1;
#endif
}

// decode 4x fp8 from u32
__device__ __forceinline__ void fp8x4f(u32 w, float& f0, float& f1, float& f2, float& f3) {
#if __has_builtin(__builtin_amdgcn_cvt_pk_f32_fp8)
    f32x2 r0 = __builtin_amdgcn_cvt_pk_f32_fp8((int)w, false);
    f32x2 r1 = __builtin_amdgcn_cvt_pk_f32_fp8((int)w, true);
    f0 = r0[0]; f1 = r0[1]; f2 = r1[0]; f3 = r1[1];
#else
    fp8x2f(w & 0xffffu, f0, f1);
    fp8x2f(w >> 16, f2, f3);
#endif
}

// packed weight layout (bf16): elem(((ks*8+nt)*64+l)*8+j) = W[ks*32+((l>>4))*8+j][nt*16+(l&15)]
#define W1OFF 0
#define W2OFF 32768
#define WSOFF 49152
#define ENCOFF 65536
#define PACKN 73728

// ---------------- setup kernels ----------------

__global__ void k_hist(const int* __restrict__ dst, int* __restrict__ hist) {
    int e = blockIdx.x * 256 + threadIdx.x;
    if (e < NE) atomicAdd(&hist[dst[e]], 1);
}

// hierarchical scan: A) per-block exclusive + block sums, B) scan block sums, C) add offsets
__global__ void k_scanA(const int* __restrict__ hist, int* __restrict__ excl,
                        int* __restrict__ bsum) {
    __shared__ int sh[256];
    int t = threadIdx.x, b = blockIdx.x;
    int idx = b * 256 + t;
    int v = (idx < NN) ? hist[idx] : 0;
    sh[t] = v;
    __syncthreads();
    for (int off = 1; off < 256; off <<= 1) {
        int add = (t >= off) ? sh[t - off] : 0;
        __syncthreads();
        sh[t] += add;
        __syncthreads();
    }
    if (idx < NN) excl[idx] = sh[t] - v;
    if (t == 255) bsum[b] = sh[255];
}

__global__ void k_scanB(int* __restrict__ bsum) {
    __shared__ int sh[256];
    int t = threadIdx.x;
    int v = (t < SCAN_B) ? bsum[t] : 0;
    sh[t] = v;
    __syncthreads();
    for (int off = 1; off < 256; off <<= 1) {
        int add = (t >= off) ? sh[t - off] : 0;
        __syncthreads();
        sh[t] += add;
        __syncthreads();
    }
    if (t < SCAN_B) bsum[t] = sh[t] - v;  // exclusive
}

__global__ void k_scanC(const int* __restrict__ excl, const int* __restrict__ bsum,
                        int* __restrict__ rowptr, int* __restrict__ cursor) {
    int idx = blockIdx.x * 256 + threadIdx.x;
    if (idx < NN) {
        int r = excl[idx] + bsum[blockIdx.x];
        rowptr[idx] = r;
        cursor[idx] = r;
    }
    if (idx == 0) rowptr[NN] = NE;
}

__global__ void k_scatter(const int* __restrict__ src, const int* __restrict__ dst,
                          const float* __restrict__ eattr, int* __restrict__ cursor,
                          int* __restrict__ ssrc, u16* __restrict__ ea8) {
    int e = blockIdx.x * 256 + threadIdx.x;
    if (e >= NE) return;
    int d = dst[e];
    int pos = atomicAdd(&cursor[d], 1);
    ssrc[pos] = src[e];
    const float* ap = eattr + (size_t)e * 8;
    uint4 w;
    w.x = (u32)f2bf(ap[0]) | ((u32)f2bf(ap[1]) << 16);
    w.y = (u32)f2bf(ap[2]) | ((u32)f2bf(ap[3]) << 16);
    w.z = (u32)f2bf(ap[4]) | ((u32)f2bf(ap[5]) << 16);
    w.w = (u32)f2bf(ap[6]) | ((u32)f2bf(ap[7]) << 16);
    *(uint4*)(ea8 + (size_t)pos * 8) = w;
}

// eaw[i][c] = fp8( sum_k ea8[i][k] * msg_w[128+k][c] )  (CSR-sorted edge order)
__global__ __launch_bounds__(256) void k_eaw(
    const u16* __restrict__ ea8, const float* __restrict__ msg_w,
    unsigned char* __restrict__ eaw) {
    __shared__ float wlds[8][128];
    int t = threadIdx.x;
    for (int i = t; i < 1024; i += 256) {
        int k = i >> 7, c = i & 127;
        wlds[k][c] = msg_w[(size_t)(128 + k) * 128 + c];
    }
    __syncthreads();
    int e = blockIdx.x * 8 + (t >> 5);
    if (e >= NE) return;
    int w = t & 31;  // channels 4w..4w+3
    uint4 ev = *(const uint4*)(ea8 + (size_t)e * 8);
    float ef[8];
    ef[0] = bf2f(ev.x & 0xffffu); ef[1] = bf2f(ev.x >> 16);
    ef[2] = bf2f(ev.y & 0xffffu); ef[3] = bf2f(ev.y >> 16);
    ef[4] = bf2f(ev.z & 0xffffu); ef[5] = bf2f(ev.z >> 16);
    ef[6] = bf2f(ev.w & 0xffffu); ef[7] = bf2f(ev.w >> 16);
    float o0 = 0.f, o1 = 0.f, o2 = 0.f, o3 = 0.f;
#pragma unroll
    for (int k = 0; k < 8; ++k) {
        float a = ef[k];
        o0 += a * wlds[k][4 * w + 0];
        o1 += a * wlds[k][4 * w + 1];
        o2 += a * wlds[k][4 * w + 2];
        o3 += a * wlds[k][4 * w + 3];
    }
    *(u32*)(eaw + (size_t)e * 128 + 4 * w) = pk4_fp8(o0, o1, o2, o3);
}

__global__ void k_pack(const float* __restrict__ up_w1, const float* __restrict__ up_w2,
                       const float* __restrict__ msg_w, const float* __restrict__ enc_w,
                       u16* __restrict__ packed) {
    int idx = blockIdx.x * 256 + threadIdx.x;
    if (idx >= PACKN) return;
    const float* srcp; int local;
    if (idx < W2OFF)        { srcp = up_w1; local = idx; }
    else if (idx < WSOFF)   { srcp = up_w2; local = idx - W2OFF; }
    else if (idx < ENCOFF)  { srcp = msg_w; local = idx - WSOFF; }   // rows 0..127 (state part)
    else                    { srcp = enc_w; local = idx - ENCOFF; }
    int j = local & 7;
    int l = (local >> 3) & 63;
    int ntks = local >> 9;
    int nt = ntks & 7;
    int ks = ntks >> 3;
    int krow = ks * 32 + (l >> 4) * 8 + j;
    int col = nt * 16 + (l & 15);
    packed[idx] = f2bf(srcp[krow * 128 + col]);
}

// ---------------- encoder: state = relu(x@enc_w+enc_b); SW = state@Ws + msg_b ----------------

__global__ __launch_bounds__(256) void k_encode(
    const float* __restrict__ x, const float* __restrict__ enc_b,
    const float* __restrict__ msg_b, const u16* __restrict__ packed,
    float* __restrict__ state_f, u16* __restrict__ state_h, u16* __restrict__ swb) {
    __shared__ u16 stage[4][2048];
    const int wv = threadIdx.x >> 6, l = threadIdx.x & 63;
    const int lr = l & 15, kb = l >> 4;
    const int rb = blockIdx.x * 64 + wv * 16;
    const int row = rb + lr;
    const int rowc = row < NN ? row : NN - 1;

    f32x4 acc[8] = {};
#pragma unroll
    for (int ks = 0; ks < 2; ++ks) {
        const float* ap = x + (size_t)rowc * 64 + ks * 32 + kb * 8;
        float4 a0 = *(const float4*)ap;
        float4 a1 = *(const float4*)(ap + 4);
        short8 a;
        a[0] = (short)f2bf(a0.x); a[1] = (short)f2bf(a0.y);
        a[2] = (short)f2bf(a0.z); a[3] = (short)f2bf(a0.w);
        a[4] = (short)f2bf(a1.x); a[5] = (short)f2bf(a1.y);
        a[6] = (short)f2bf(a1.z); a[7] = (short)f2bf(a1.w);
        const u16* bp = packed + ENCOFF + (size_t)(ks * 512 + l) * 8;
#pragma unroll
        for (int nt = 0; nt < 8; ++nt) {
            short8 b = *(const short8*)(bp + nt * 512);
            acc[nt] = mfma16(a, b, acc[nt]);
        }
    }
#pragma unroll
    for (int nt = 0; nt < 8; ++nt) {
        int col = nt * 16 + lr;
        float bias = enc_b[col];
#pragma unroll
        for (int j = 0; j < 4; ++j) {
            int rl = kb * 4 + j;
            int r = rb + rl;
            float v = acc[nt][j] + bias;
            v = v > 0.f ? v : 0.f;
            u16 h = f2bf(v);
            if (r < NN) {
                state_f[(size_t)r * 128 + col] = v;
                state_h[(size_t)r * 128 + col] = h;
            }
            int byte = (rl * 256 + col * 2) ^ ((rl & 7) << 4);
            *(u16*)((char*)stage[wv] + byte) = h;
        }
    }
    f32x4 acc3[8] = {};
#pragma unroll
    for (int ks = 0; ks < 4; ++ks) {
        int byte = (lr * 256 + ks * 64 + kb * 16) ^ ((lr & 7) << 4);
        short8 a = *(const short8*)((char*)stage[wv] + byte);
        const u16* bp = packed + WSOFF + (size_t)(ks * 512 + l) * 8;
#pragma unroll
        for (int nt = 0; nt < 8; ++nt) {
            short8 b = *(const short8*)(bp + nt * 512);
            acc3[nt] = mfma16(a, b, acc3[nt]);
        }
    }
#pragma unroll
    for (int nt = 0; nt < 8; ++nt) {
        int col = nt * 16 + lr;
        float bias = msg_b[col];
#pragma unroll
        for (int j = 0; j < 4; ++j) {
            int r = rb + kb * 4 + j;
            if (r < NN) swb[(size_t)r * 128 + col] = f2bf(acc3[nt][j] + bias);
        }
    }
}

// ---------------- edge kernel: agg[n] = mean_e relu(SW[src_e] + EAW[e]) ----------------
// 2 nodes per wave: 32 lanes/node, 4 channels/lane

__global__ __launch_bounds__(256) void k_edge(
    const int* __restrict__ rowptr, const int* __restrict__ ssrc,
    const unsigned char* __restrict__ eaw, const u16* __restrict__ swb,
    u16* __restrict__ aggb) {
    const int wv = threadIdx.x >> 6, l = threadIdx.x & 63;
    const int half = l >> 5, lo = l & 31;
    const int n = blockIdx.x * 8 + wv * 2 + half;
    if (n >= NN) return;
    const int e0 = rowptr[n], e1 = rowptr[n + 1];
    float a0 = 0.f, a1 = 0.f, a2 = 0.f, a3 = 0.f;
#pragma unroll 4
    for (int i = e0; i < e1; ++i) {
        int s = ssrc[i];
        u32 q = *(const u32*)(eaw + (size_t)i * 128 + 4 * lo);
        uint2 swp = *(const uint2*)(swb + (size_t)s * 128 + 4 * lo);
        float ex0, ex1, ex2, ex3;
        fp8x4f(q, ex0, ex1, ex2, ex3);
        union { u32 i; float f; } w0, w1, w2, w3;
        w0.i = swp.x << 16;
        w1.i = swp.x & 0xffff0000u;
        w2.i = swp.y << 16;
        w3.i = swp.y & 0xffff0000u;
        float m0 = w0.f + ex0, m1 = w1.f + ex1, m2 = w2.f + ex2, m3 = w3.f + ex3;
        a0 += m0 > 0.f ? m0 : 0.f;
        a1 += m1 > 0.f ? m1 : 0.f;
        a2 += m2 > 0.f ? m2 : 0.f;
        a3 += m3 > 0.f ? m3 : 0.f;
    }
    int dg = e1 - e0;
    float inv = 1.f / (float)(dg > 0 ? dg : 1);
    uint2 outw;
    outw.x = (u32)f2bf(a0 * inv) | ((u32)f2bf(a1 * inv) << 16);
    outw.y = (u32)f2bf(a2 * inv) | ((u32)f2bf(a3 * inv) << 16);
    *(uint2*)(aggb + (size_t)n * 128 + 4 * lo) = outw;
}

// ---------------- update kernel (R=2 row tiles/wave, direct global B): ----------------
// h=relu([state,agg]@W1+b1); state+=h@W2+b2; SW=state@Ws+msg_b

__global__ __launch_bounds__(256) void k_update(
    const float* __restrict__ up_b1, const float* __restrict__ up_b2,
    const float* __restrict__ msg_b, const u16* __restrict__ packed,
    const u16* __restrict__ aggb, float* __restrict__ state_f,
    u16* __restrict__ state_h, u16* __restrict__ swb) {
    __shared__ u16 stage[4][2][2048];
    const int wv = threadIdx.x >> 6, l = threadIdx.x & 63;
    const int lr = l & 15, kb = l >> 4;
    const int rbase = blockIdx.x * 128 + wv * 32;

    // GEMM1: K=256 over [state_h, aggb], 2 row tiles
    f32x4 acc[2][8] = {};
#pragma unroll
    for (int ks = 0; ks < 8; ++ks) {
        short8 a[2];
#pragma unroll
        for (int rt = 0; rt < 2; ++rt) {
            int row = rbase + rt * 16 + lr;
            int rowc = row < NN ? row : NN - 1;
            const u16* abase = (ks < 4)
                ? (state_h + (size_t)rowc * 128 + ks * 32 + kb * 8)
                : (aggb + (size_t)rowc * 128 + (ks - 4) * 32 + kb * 8);
            a[rt] = *(const short8*)abase;
        }
        const u16* bp = packed + W1OFF + (size_t)(ks * 512 + l) * 8;
#pragma unroll
        for (int nt = 0; nt < 8; ++nt) {
            short8 b = *(const short8*)(bp + nt * 512);
            acc[0][nt] = mfma16(a[0], b, acc[0][nt]);
            acc[1][nt] = mfma16(a[1], b, acc[1][nt]);
        }
    }
    // h = relu(acc + b1) -> stage
#pragma unroll
    for (int nt = 0; nt < 8; ++nt) {
        int col = nt * 16 + lr;
        float b1v = up_b1[col];
#pragma unroll
        for (int rt = 0; rt < 2; ++rt) {
#pragma unroll
            for (int j = 0; j < 4; ++j) {
                int rl = kb * 4 + j;
                float v = acc[rt][nt][j] + b1v;
                v = v > 0.f ? v : 0.f;
                int byte = (rl * 256 + col * 2) ^ ((rl & 7) << 4);
                *(u16*)((char*)stage[wv][rt] + byte) = f2bf(v);
            }
        }
    }
    // GEMM2: delta = h @ W2
    f32x4 acc2[2][8] = {};
#pragma unroll
    for (int ks = 0; ks < 4; ++ks) {
        int byte = (lr * 256 + ks * 64 + kb * 16) ^ ((lr & 7) << 4);
        short8 a[2];
        a[0] = *(const short8*)((char*)stage[wv][0] + byte);
        a[1] = *(const short8*)((char*)stage[wv][1] + byte);
        const u16* bp = packed + W2OFF + (size_t)(ks * 512 + l) * 8;
#pragma unroll
        for (int nt = 0; nt < 8; ++nt) {
            short8 b = *(const short8*)(bp + nt * 512);
            acc2[0][nt] = mfma16(a[0], b, acc2[0][nt]);
            acc2[1][nt] = mfma16(a[1], b, acc2[1][nt]);
        }
    }
    // state += delta + b2 ; stage <- state_new (bf16) [wave-local, in-order]
#pragma unroll
    for (int rt = 0; rt < 2; ++rt) {
#pragma unroll
        for (int nt = 0; nt < 8; ++nt) {
            int col = nt * 16 + lr;
            float b2v = up_b2[col];
#pragma unroll
            for (int j = 0; j < 4; ++j) {
                int rl = kb * 4 + j;
                int r = rbase + rt * 16 + rl;
                int rc = r < NN ? r : NN - 1;
                float snew = state_f[(size_t)rc * 128 + col] + acc2[rt][nt][j] + b2v;
                u16 hb = f2bf(snew);
                if (r < NN) {
                    state_f[(size_t)r * 128 + col] = snew;
                    state_h[(size_t)r * 128 + col] = hb;
                }
                int byte = (rl * 256 + col * 2) ^ ((rl & 7) << 4);
                *(u16*)((char*)stage[wv][rt] + byte) = hb;
            }
        }
    }
    // GEMM3: SW = state_new @ Ws + msg_b
    f32x4 acc3[2][8] = {};
#pragma unroll
    for (int ks = 0; ks < 4; ++ks) {
        int byte = (lr * 256 + ks * 64 + kb * 16) ^ ((lr & 7) << 4);
        short8 a[2];
        a[0] = *(const short8*)((char*)stage[wv][0] + byte);
        a[1] = *(const short8*)((char*)stage[wv][1] + byte);
        const u16* bp = packed + WSOFF + (size_t)(ks * 512 + l) * 8;
#pragma unroll
        for (int nt = 0; nt < 8; ++nt) {
            short8 b = *(const short8*)(bp + nt * 512);
            acc3[0][nt] = mfma16(a[0], b, acc3[0][nt]);
            acc3[1][nt] = mfma16(a[1], b, acc3[1][nt]);
        }
    }
#pragma unroll
    for (int rt = 0; rt < 2; ++rt) {
#pragma unroll
        for (int nt = 0; nt < 8; ++nt) {
            int col = nt * 16 + lr;
            float bias = msg_b[col];
#pragma unroll
            for (int j = 0; j < 4; ++j) {
                int r = rbase + rt * 16 + kb * 4 + j;
                if (r < NN) swb[(size_t)r * 128 + col] = f2bf(acc3[rt][nt][j] + bias);
            }
        }
    }
}

// ---------------- logits: deterministic batched segment mean over sorted batch ----------------

__global__ void k_logits(const float* __restrict__ state_f, const int* __restrict__ batch,
                         float* __restrict__ out) {
    __shared__ float red[256];
    int b = blockIdx.x, t = threadIdx.x;
    int ch = t & 7, sub = t >> 3;
    int lo = 0, hi = NN;
    while (lo < hi) { int m = (lo + hi) >> 1; if (batch[m] < b) lo = m + 1; else hi = m; }
    int s0 = lo;
    lo = 0; hi = NN;
    while (lo < hi) { int m = (lo + hi) >> 1; if (batch[m] < b + 1) lo = m + 1; else hi = m; }
    int s1 = lo;
    float acc = 0.f;
    for (int n = s0 + sub; n < s1; n += 32)
        acc += state_f[(size_t)n * 128 + 120 + ch];
    red[t] = acc;
    __syncthreads();
    for (int off = 16; off >= 1; off >>= 1) {
        if (sub < off) red[t] += red[t + off * 8];
        __syncthreads();
    }
    if (sub == 0) {
        int c = s1 - s0;
        float cnt = (float)(c > 0 ? c : 1);
        out[b * 8 + ch] = red[ch] / cnt;
    }
}

// ---------------- launch ----------------

extern "C" void kernel_launch(void* const* d_in, const int* in_sizes, int n_in,
                              void* d_out, int out_size, void* d_ws, size_t ws_size,
                              hipStream_t stream) {
    (void)in_sizes; (void)n_in;
    const float* x      = (const float*)d_in[0];
    const int*   eidx   = (const int*)d_in[1];
    const float* eattr  = (const float*)d_in[2];
    const int*   batch  = (const int*)d_in[3];
    const float* enc_w  = (const float*)d_in[4];
    const float* enc_b  = (const float*)d_in[5];
    const float* msg_w  = (const float*)d_in[6];
    const float* msg_b  = (const float*)d_in[7];
    const float* up_w1  = (const float*)d_in[8];
    const float* up_b1  = (const float*)d_in[9];
    const float* up_w2  = (const float*)d_in[10];
    const float* up_b2  = (const float*)d_in[11];
    const int* esrc = eidx;
    const int* edst = eidx + NE;

    char* p = (char*)d_ws;
    size_t off = 0;
    auto carve = [&](size_t bytes) -> char* {
        char* r = p + off;
        off += (bytes + 255) & ~(size_t)255;
        return r;
    };
    float* state_f = (float*)carve((size_t)NN * 128 * 4);
    u16* state_h   = (u16*)carve((size_t)NN * 128 * 2);
    u16* aggb      = (u16*)carve((size_t)NN * 128 * 2);
    u16* swb       = (u16*)carve((size_t)NN * 128 * 2);
    int* ssrc      = (int*)carve((size_t)NE * 4);
    u16* ea8       = (u16*)carve((size_t)NE * 8 * 2);
    unsigned char* eaw = (unsigned char*)carve((size_t)NE * 128);
    int* rowptr    = (int*)carve((size_t)(NN + 1) * 4);
    int* cursor    = (int*)carve((size_t)NN * 4);
    int* hist      = (int*)carve((size_t)NN * 4);
    int* sexcl     = (int*)carve((size_t)NN * 4);
    int* bsum      = (int*)carve((size_t)256 * 4);
    u16* packed    = (u16*)carve((size_t)PACKN * 2);
    if (off > ws_size) {
        // sentinel: NaN output tells us the workspace was too small
        hipMemsetAsync(d_out, 0xFF, (size_t)out_size * 4, stream);
        return;
    }

    hipMemsetAsync(hist, 0, (size_t)NN * 4, stream);
    k_hist<<<(NE + 255) / 256, 256, 0, stream>>>(edst, hist);
    k_scanA<<<SCAN_B, 256, 0, stream>>>(hist, sexcl, bsum);
    k_scanB<<<1, 256, 0, stream>>>(bsum);
    k_scanC<<<SCAN_B, 256, 0, stream>>>(sexcl, bsum, rowptr, cursor);
    k_scatter<<<(NE + 255) / 256, 256, 0, stream>>>(esrc, edst, eattr, cursor, ssrc, ea8);
    k_eaw<<<(NE + 7) / 8, 256, 0, stream>>>(ea8, msg_w, eaw);
    k_pack<<<(PACKN + 255) / 256, 256, 0, stream>>>(up_w1, up_w2, msg_w, enc_w, packed);
    k_encode<<<(NN + 63) / 64, 256, 0, stream>>>(x, enc_b, msg_b, packed, state_f, state_h, swb);
    for (int t = 0; t < T_STEPS; ++t) {
        k_edge<<<(NN + 7) / 8, 256, 0, stream>>>(rowptr, ssrc, eaw, swb, aggb);
        k_update<<<(NN + 127) / 128, 256, 0, stream>>>(up_b1, up_b2, msg_b, packed, aggb,
                                                       state_f, state_h, swb);
    }
    k_logits<<<NB, 256, 0, stream>>>(state_f, batch, (float*)d_out);
}

// Round 5
// 1217.481 us; speedup vs baseline: 1.2265x; 1.0219x over previous
//
#include <hip/hip_runtime.h>
#include <hip/hip_bf16.h>

#define NN 50000
#define NE 800000
#define NB 16
#define T_STEPS 12
#define SCAN_B 196  // ceil(NN/256)
#define EAW_BLOCKS 1024

typedef __attribute__((ext_vector_type(8))) short short8;
typedef __attribute__((ext_vector_type(4))) float f32x4;
typedef __attribute__((ext_vector_type(2))) float f32x2;
typedef unsigned short u16;
typedef unsigned int u32;

__device__ __forceinline__ float bf2f(u32 u) {
    union { u32 i; float f; } v; v.i = u << 16; return v.f;
}
__device__ __forceinline__ u16 f2bf(float f) {
    union { float f; u32 i; } v; v.f = f;
    u32 r = v.i + 0x7fffu + ((v.i >> 16) & 1u);
    return (u16)(r >> 16);
}
__device__ __forceinline__ f32x4 mfma16(short8 a, short8 b, f32x4 c) {
    return __builtin_amdgcn_mfma_f32_16x16x32_bf16(a, b, c, 0, 0, 0);
}

// pack 2 floats -> fp8 e4m3 pair in low 16 bits (HW instruction; OCP on gfx950)
__device__ __forceinline__ u32 pk2_fp8(float o0, float o1) {
#if __has_builtin(__builtin_amdgcn_cvt_pk_fp8_f32)
    return (u32)__builtin_amdgcn_cvt_pk_fp8_f32(o0, o1, 0, false);
#else
    u32 a = 0;
    asm("v_cvt_pk_fp8_f32 %0, %1, %2" : "+v"(a) : "v"(o0), "v"(o1));
    return a;
#endif
}
__device__ __forceinline__ u32 pk4_fp8(float o0, float o1, float o2, float o3) {
    return (pk2_fp8(o0, o1) & 0xffffu) | (pk2_fp8(o2, o3) << 16);
}

// decode 4x fp8 e4m3 from u32
__device__ __forceinline__ void fp8x4f(u32 w, float& f0, float& f1, float& f2, float& f3) {
#if __has_builtin(__builtin_amdgcn_cvt_pk_f32_fp8)
    f32x2 r0 = __builtin_amdgcn_cvt_pk_f32_fp8((int)w, false);
    f32x2 r1 = __builtin_amdgcn_cvt_pk_f32_fp8((int)w, true);
    f0 = r0[0]; f1 = r0[1]; f2 = r1[0]; f3 = r1[1];
#else
    f32x2 r0, r1;
    u32 hi = w >> 16;
    asm("v_cvt_pk_f32_fp8 %0, %1" : "=v"(r0) : "v"(w));
    asm("v_cvt_pk_f32_fp8 %0, %1" : "=v"(r1) : "v"(hi));
    f0 = r0[0]; f1 = r0[1]; f2 = r1[0]; f3 = r1[1];
#endif
}

// packed weight layout (bf16): elem(((ks*8+nt)*64+l)*8+j) = W[ks*32+((l>>4))*8+j][nt*16+(l&15)]
#define W1OFF 0
#define W2OFF 32768
#define WSOFF 49152
#define ENCOFF 65536
#define PACKN 73728

// ---------------- setup kernels ----------------

__global__ void k_hist(const int* __restrict__ dst, int* __restrict__ hist) {
    int e = blockIdx.x * 256 + threadIdx.x;
    if (e < NE) atomicAdd(&hist[dst[e]], 1);
}

// hierarchical scan: A) per-block exclusive + block sums, B) scan block sums, C) add offsets
__global__ void k_scanA(const int* __restrict__ hist, int* __restrict__ excl,
                        int* __restrict__ bsum) {
    __shared__ int sh[256];
    int t = threadIdx.x, b = blockIdx.x;
    int idx = b * 256 + t;
    int v = (idx < NN) ? hist[idx] : 0;
    sh[t] = v;
    __syncthreads();
    for (int off = 1; off < 256; off <<= 1) {
        int add = (t >= off) ? sh[t - off] : 0;
        __syncthreads();
        sh[t] += add;
        __syncthreads();
    }
    if (idx < NN) excl[idx] = sh[t] - v;
    if (t == 255) bsum[b] = sh[255];
}

__global__ void k_scanB(int* __restrict__ bsum) {
    __shared__ int sh[256];
    int t = threadIdx.x;
    int v = (t < SCAN_B) ? bsum[t] : 0;
    sh[t] = v;
    __syncthreads();
    for (int off = 1; off < 256; off <<= 1) {
        int add = (t >= off) ? sh[t - off] : 0;
        __syncthreads();
        sh[t] += add;
        __syncthreads();
    }
    if (t < SCAN_B) bsum[t] = sh[t] - v;  // exclusive
}

__global__ void k_scanC(const int* __restrict__ excl, const int* __restrict__ bsum,
                        int* __restrict__ rowptr, int* __restrict__ cursor) {
    int idx = blockIdx.x * 256 + threadIdx.x;
    if (idx < NN) {
        int r = excl[idx] + bsum[blockIdx.x];
        rowptr[idx] = r;
        cursor[idx] = r;
    }
    if (idx == 0) rowptr[NN] = NE;
}

__global__ void k_scatter(const int* __restrict__ src, const int* __restrict__ dst,
                          const float* __restrict__ eattr, int* __restrict__ cursor,
                          int* __restrict__ ssrc, u16* __restrict__ ea8) {
    int e = blockIdx.x * 256 + threadIdx.x;
    if (e >= NE) return;
    int d = dst[e];
    int pos = atomicAdd(&cursor[d], 1);
    ssrc[pos] = src[e];
    const float* ap = eattr + (size_t)e * 8;
    uint4 w;
    w.x = (u32)f2bf(ap[0]) | ((u32)f2bf(ap[1]) << 16);
    w.y = (u32)f2bf(ap[2]) | ((u32)f2bf(ap[3]) << 16);
    w.z = (u32)f2bf(ap[4]) | ((u32)f2bf(ap[5]) << 16);
    w.w = (u32)f2bf(ap[6]) | ((u32)f2bf(ap[7]) << 16);
    *(uint4*)(ea8 + (size_t)pos * 8) = w;
}

// eaw[e][c] = fp8( sum_k ea8[e][k] * msg_w[128+k][c] )  (CSR-sorted edge order)
// grid-stride; lane = (edge, 16-ch oct); weights in VGPRs; no LDS, no barrier.
__global__ __launch_bounds__(256) void k_eaw(
    const u16* __restrict__ ea8, const float* __restrict__ msg_w,
    unsigned char* __restrict__ eaw) {
    const int tid = threadIdx.x;
    const int oct = tid & 7;    // channel slice [oct*16, oct*16+16)
    const int esub = tid >> 3;  // 0..31
    float w[8][16];
#pragma unroll
    for (int k = 0; k < 8; ++k) {
#pragma unroll
        for (int c4 = 0; c4 < 4; ++c4) {
            float4 v = *(const float4*)(msg_w + (size_t)(128 + k) * 128 + oct * 16 + c4 * 4);
            w[k][c4 * 4 + 0] = v.x; w[k][c4 * 4 + 1] = v.y;
            w[k][c4 * 4 + 2] = v.z; w[k][c4 * 4 + 3] = v.w;
        }
    }
    int e = blockIdx.x * 32 + esub;
    if (e >= NE) return;
    uint4 ev = *(const uint4*)(ea8 + (size_t)e * 8);
    while (true) {
        int en = e + EAW_BLOCKS * 32;
        bool more = en < NE;
        uint4 evn;
        if (more) evn = *(const uint4*)(ea8 + (size_t)en * 8);
        float ef[8];
        ef[0] = bf2f(ev.x & 0xffffu); ef[1] = bf2f(ev.x >> 16);
        ef[2] = bf2f(ev.y & 0xffffu); ef[3] = bf2f(ev.y >> 16);
        ef[4] = bf2f(ev.z & 0xffffu); ef[5] = bf2f(ev.z >> 16);
        ef[6] = bf2f(ev.w & 0xffffu); ef[7] = bf2f(ev.w >> 16);
        float o[16];
#pragma unroll
        for (int c = 0; c < 16; ++c) o[c] = ef[0] * w[0][c];
#pragma unroll
        for (int k = 1; k < 8; ++k)
#pragma unroll
            for (int c = 0; c < 16; ++c) o[c] += ef[k] * w[k][c];
        uint4 q;
        q.x = pk4_fp8(o[0], o[1], o[2], o[3]);
        q.y = pk4_fp8(o[4], o[5], o[6], o[7]);
        q.z = pk4_fp8(o[8], o[9], o[10], o[11]);
        q.w = pk4_fp8(o[12], o[13], o[14], o[15]);
        *(uint4*)(eaw + (size_t)e * 128 + oct * 16) = q;
        if (!more) break;
        ev = evn;
        e = en;
    }
}

__global__ void k_pack(const float* __restrict__ up_w1, const float* __restrict__ up_w2,
                       const float* __restrict__ msg_w, const float* __restrict__ enc_w,
                       u16* __restrict__ packed) {
    int idx = blockIdx.x * 256 + threadIdx.x;
    if (idx >= PACKN) return;
    const float* srcp; int local;
    if (idx < W2OFF)        { srcp = up_w1; local = idx; }
    else if (idx < WSOFF)   { srcp = up_w2; local = idx - W2OFF; }
    else if (idx < ENCOFF)  { srcp = msg_w; local = idx - WSOFF; }   // rows 0..127 (state part)
    else                    { srcp = enc_w; local = idx - ENCOFF; }
    int j = local & 7;
    int l = (local >> 3) & 63;
    int ntks = local >> 9;
    int nt = ntks & 7;
    int ks = ntks >> 3;
    int krow = ks * 32 + (l >> 4) * 8 + j;
    int col = nt * 16 + (l & 15);
    packed[idx] = f2bf(srcp[krow * 128 + col]);
}

// ---------------- encoder: state = relu(x@enc_w+enc_b); SW = state@Ws + msg_b ----------------

__global__ __launch_bounds__(256) void k_encode(
    const float* __restrict__ x, const float* __restrict__ enc_b,
    const float* __restrict__ msg_b, const u16* __restrict__ packed,
    float* __restrict__ state_f, u16* __restrict__ state_h, u16* __restrict__ swb) {
    __shared__ u16 stage[4][2048];
    const int wv = threadIdx.x >> 6, l = threadIdx.x & 63;
    const int lr = l & 15, kb = l >> 4;
    const int rb = blockIdx.x * 64 + wv * 16;
    const int row = rb + lr;
    const int rowc = row < NN ? row : NN - 1;

    f32x4 acc[8] = {};
#pragma unroll
    for (int ks = 0; ks < 2; ++ks) {
        const float* ap = x + (size_t)rowc * 64 + ks * 32 + kb * 8;
        float4 a0 = *(const float4*)ap;
        float4 a1 = *(const float4*)(ap + 4);
        short8 a;
        a[0] = (short)f2bf(a0.x); a[1] = (short)f2bf(a0.y);
        a[2] = (short)f2bf(a0.z); a[3] = (short)f2bf(a0.w);
        a[4] = (short)f2bf(a1.x); a[5] = (short)f2bf(a1.y);
        a[6] = (short)f2bf(a1.z); a[7] = (short)f2bf(a1.w);
        const u16* bp = packed + ENCOFF + (size_t)(ks * 512 + l) * 8;
#pragma unroll
        for (int nt = 0; nt < 8; ++nt) {
            short8 b = *(const short8*)(bp + nt * 512);
            acc[nt] = mfma16(a, b, acc[nt]);
        }
    }
#pragma unroll
    for (int nt = 0; nt < 8; ++nt) {
        int col = nt * 16 + lr;
        float bias = enc_b[col];
#pragma unroll
        for (int j = 0; j < 4; ++j) {
            int rl = kb * 4 + j;
            int r = rb + rl;
            float v = acc[nt][j] + bias;
            v = v > 0.f ? v : 0.f;
            u16 h = f2bf(v);
            if (r < NN) {
                state_f[(size_t)r * 128 + col] = v;
                state_h[(size_t)r * 128 + col] = h;
            }
            int byte = (rl * 256 + col * 2) ^ ((rl & 7) << 4);
            *(u16*)((char*)stage[wv] + byte) = h;
        }
    }
    f32x4 acc3[8] = {};
#pragma unroll
    for (int ks = 0; ks < 4; ++ks) {
        int byte = (lr * 256 + ks * 64 + kb * 16) ^ ((lr & 7) << 4);
        short8 a = *(const short8*)((char*)stage[wv] + byte);
        const u16* bp = packed + WSOFF + (size_t)(ks * 512 + l) * 8;
#pragma unroll
        for (int nt = 0; nt < 8; ++nt) {
            short8 b = *(const short8*)(bp + nt * 512);
            acc3[nt] = mfma16(a, b, acc3[nt]);
        }
    }
#pragma unroll
    for (int nt = 0; nt < 8; ++nt) {
        int col = nt * 16 + lr;
        float bias = msg_b[col];
#pragma unroll
        for (int j = 0; j < 4; ++j) {
            int r = rb + kb * 4 + j;
            if (r < NN) swb[(size_t)r * 128 + col] = f2bf(acc3[nt][j] + bias);
        }
    }
}

// ---------------- edge kernel: agg[n] = mean_e relu(SW[src_e] + EAW[e]) ----------------
// 2 nodes per wave: 32 lanes/node, 4 channels/lane

__global__ __launch_bounds__(256) void k_edge(
    const int* __restrict__ rowptr, const int* __restrict__ ssrc,
    const unsigned char* __restrict__ eaw, const u16* __restrict__ swb,
    u16* __restrict__ aggb) {
    const int wv = threadIdx.x >> 6, l = threadIdx.x & 63;
    const int half = l >> 5, lo = l & 31;
    const int n = blockIdx.x * 8 + wv * 2 + half;
    if (n >= NN) return;
    const int e0 = rowptr[n], e1 = rowptr[n + 1];
    const unsigned char* ep = eaw + (size_t)e0 * 128 + 4 * lo;
    const u16* swbase = swb + 4 * lo;
    float a0 = 0.f, a1 = 0.f, a2 = 0.f, a3 = 0.f;
#pragma unroll 4
    for (int i = e0; i < e1; ++i) {
        int s = ssrc[i];
        u32 q = *(const u32*)ep;
        ep += 128;
        uint2 swp = *(const uint2*)(swbase + (size_t)s * 128);
        float ex0, ex1, ex2, ex3;
        fp8x4f(q, ex0, ex1, ex2, ex3);
        union { u32 i; float f; } w0, w1, w2, w3;
        w0.i = swp.x << 16;
        w1.i = swp.x & 0xffff0000u;
        w2.i = swp.y << 16;
        w3.i = swp.y & 0xffff0000u;
        float m0 = w0.f + ex0, m1 = w1.f + ex1, m2 = w2.f + ex2, m3 = w3.f + ex3;
        a0 += m0 > 0.f ? m0 : 0.f;
        a1 += m1 > 0.f ? m1 : 0.f;
        a2 += m2 > 0.f ? m2 : 0.f;
        a3 += m3 > 0.f ? m3 : 0.f;
    }
    int dg = e1 - e0;
    float inv = 1.f / (float)(dg > 0 ? dg : 1);
    uint2 outw;
    outw.x = (u32)f2bf(a0 * inv) | ((u32)f2bf(a1 * inv) << 16);
    outw.y = (u32)f2bf(a2 * inv) | ((u32)f2bf(a3 * inv) << 16);
    *(uint2*)(aggb + (size_t)n * 128 + 4 * lo) = outw;
}

// ---------------- update kernel (R=2 row tiles/wave, direct global B): ----------------
// h=relu([state,agg]@W1+b1); state+=h@W2+b2; SW=state@Ws+msg_b

__global__ __launch_bounds__(256) void k_update(
    const float* __restrict__ up_b1, const float* __restrict__ up_b2,
    const float* __restrict__ msg_b, const u16* __restrict__ packed,
    const u16* __restrict__ aggb, float* __restrict__ state_f,
    u16* __restrict__ state_h, u16* __restrict__ swb) {
    __shared__ u16 stage[4][2][2048];
    const int wv = threadIdx.x >> 6, l = threadIdx.x & 63;
    const int lr = l & 15, kb = l >> 4;
    const int rbase = blockIdx.x * 128 + wv * 32;

    // GEMM1: K=256 over [state_h, aggb], 2 row tiles
    f32x4 acc[2][8] = {};
#pragma unroll
    for (int ks = 0; ks < 8; ++ks) {
        short8 a[2];
#pragma unroll
        for (int rt = 0; rt < 2; ++rt) {
            int row = rbase + rt * 16 + lr;
            int rowc = row < NN ? row : NN - 1;
            const u16* abase = (ks < 4)
                ? (state_h + (size_t)rowc * 128 + ks * 32 + kb * 8)
                : (aggb + (size_t)rowc * 128 + (ks - 4) * 32 + kb * 8);
            a[rt] = *(const short8*)abase;
        }
        const u16* bp = packed + W1OFF + (size_t)(ks * 512 + l) * 8;
#pragma unroll
        for (int nt = 0; nt < 8; ++nt) {
            short8 b = *(const short8*)(bp + nt * 512);
            acc[0][nt] = mfma16(a[0], b, acc[0][nt]);
            acc[1][nt] = mfma16(a[1], b, acc[1][nt]);
        }
    }
    // h = relu(acc + b1) -> stage
#pragma unroll
    for (int nt = 0; nt < 8; ++nt) {
        int col = nt * 16 + lr;
        float b1v = up_b1[col];
#pragma unroll
        for (int rt = 0; rt < 2; ++rt) {
#pragma unroll
            for (int j = 0; j < 4; ++j) {
                int rl = kb * 4 + j;
                float v = acc[rt][nt][j] + b1v;
                v = v > 0.f ? v : 0.f;
                int byte = (rl * 256 + col * 2) ^ ((rl & 7) << 4);
                *(u16*)((char*)stage[wv][rt] + byte) = f2bf(v);
            }
        }
    }
    // GEMM2: delta = h @ W2
    f32x4 acc2[2][8] = {};
#pragma unroll
    for (int ks = 0; ks < 4; ++ks) {
        int byte = (lr * 256 + ks * 64 + kb * 16) ^ ((lr & 7) << 4);
        short8 a[2];
        a[0] = *(const short8*)((char*)stage[wv][0] + byte);
        a[1] = *(const short8*)((char*)stage[wv][1] + byte);
        const u16* bp = packed + W2OFF + (size_t)(ks * 512 + l) * 8;
#pragma unroll
        for (int nt = 0; nt < 8; ++nt) {
            short8 b = *(const short8*)(bp + nt * 512);
            acc2[0][nt] = mfma16(a[0], b, acc2[0][nt]);
            acc2[1][nt] = mfma16(a[1], b, acc2[1][nt]);
        }
    }
    // state += delta + b2 ; stage <- state_new (bf16) [wave-local, in-order]
#pragma unroll
    for (int rt = 0; rt < 2; ++rt) {
#pragma unroll
        for (int nt = 0; nt < 8; ++nt) {
            int col = nt * 16 + lr;
            float b2v = up_b2[col];
#pragma unroll
            for (int j = 0; j < 4; ++j) {
                int rl = kb * 4 + j;
                int r = rbase + rt * 16 + rl;
                int rc = r < NN ? r : NN - 1;
                float snew = state_f[(size_t)rc * 128 + col] + acc2[rt][nt][j] + b2v;
                u16 hb = f2bf(snew);
                if (r < NN) {
                    state_f[(size_t)r * 128 + col] = snew;
                    state_h[(size_t)r * 128 + col] = hb;
                }
                int byte = (rl * 256 + col * 2) ^ ((rl & 7) << 4);
                *(u16*)((char*)stage[wv][rt] + byte) = hb;
            }
        }
    }
    // GEMM3: SW = state_new @ Ws + msg_b
    f32x4 acc3[2][8] = {};
#pragma unroll
    for (int ks = 0; ks < 4; ++ks) {
        int byte = (lr * 256 + ks * 64 + kb * 16) ^ ((lr & 7) << 4);
        short8 a[2];
        a[0] = *(const short8*)((char*)stage[wv][0] + byte);
        a[1] = *(const short8*)((char*)stage[wv][1] + byte);
        const u16* bp = packed + WSOFF + (size_t)(ks * 512 + l) * 8;
#pragma unroll
        for (int nt = 0; nt < 8; ++nt) {
            short8 b = *(const short8*)(bp + nt * 512);
            acc3[0][nt] = mfma16(a[0], b, acc3[0][nt]);
            acc3[1][nt] = mfma16(a[1], b, acc3[1][nt]);
        }
    }
#pragma unroll
    for (int rt = 0; rt < 2; ++rt) {
#pragma unroll
        for (int nt = 0; nt < 8; ++nt) {
            int col = nt * 16 + lr;
            float bias = msg_b[col];
#pragma unroll
            for (int j = 0; j < 4; ++j) {
                int r = rbase + rt * 16 + kb * 4 + j;
                if (r < NN) swb[(size_t)r * 128 + col] = f2bf(acc3[rt][nt][j] + bias);
            }
        }
    }
}

// ---------------- logits: deterministic batched segment mean over sorted batch ----------------

__global__ void k_logits(const float* __restrict__ state_f, const int* __restrict__ batch,
                         float* __restrict__ out) {
    __shared__ float red[256];
    int b = blockIdx.x, t = threadIdx.x;
    int ch = t & 7, sub = t >> 3;
    int lo = 0, hi = NN;
    while (lo < hi) { int m = (lo + hi) >> 1; if (batch[m] < b) lo = m + 1; else hi = m; }
    int s0 = lo;
    lo = 0; hi = NN;
    while (lo < hi) { int m = (lo + hi) >> 1; if (batch[m] < b + 1) lo = m + 1; else hi = m; }
    int s1 = lo;
    float acc = 0.f;
    for (int n = s0 + sub; n < s1; n += 32)
        acc += state_f[(size_t)n * 128 + 120 + ch];
    red[t] = acc;
    __syncthreads();
    for (int off = 16; off >= 1; off >>= 1) {
        if (sub < off) red[t] += red[t + off * 8];
        __syncthreads();
    }
    if (sub == 0) {
        int c = s1 - s0;
        float cnt = (float)(c > 0 ? c : 1);
        out[b * 8 + ch] = red[ch] / cnt;
    }
}

// ---------------- launch ----------------

extern "C" void kernel_launch(void* const* d_in, const int* in_sizes, int n_in,
                              void* d_out, int out_size, void* d_ws, size_t ws_size,
                              hipStream_t stream) {
    (void)in_sizes; (void)n_in;
    const float* x      = (const float*)d_in[0];
    const int*   eidx   = (const int*)d_in[1];
    const float* eattr  = (const float*)d_in[2];
    const int*   batch  = (const int*)d_in[3];
    const float* enc_w  = (const float*)d_in[4];
    const float* enc_b  = (const float*)d_in[5];
    const float* msg_w  = (const float*)d_in[6];
    const float* msg_b  = (const float*)d_in[7];
    const float* up_w1  = (const float*)d_in[8];
    const float* up_b1  = (const float*)d_in[9];
    const float* up_w2  = (const float*)d_in[10];
    const float* up_b2  = (const float*)d_in[11];
    const int* esrc = eidx;
    const int* edst = eidx + NE;

    char* p = (char*)d_ws;
    size_t off = 0;
    auto carve = [&](size_t bytes) -> char* {
        char* r = p + off;
        off += (bytes + 255) & ~(size_t)255;
        return r;
    };
    float* state_f = (float*)carve((size_t)NN * 128 * 4);
    u16* state_h   = (u16*)carve((size_t)NN * 128 * 2);
    u16* aggb      = (u16*)carve((size_t)NN * 128 * 2);
    u16* swb       = (u16*)carve((size_t)NN * 128 * 2);
    int* ssrc      = (int*)carve((size_t)NE * 4);
    u16* ea8       = (u16*)carve((size_t)NE * 8 * 2);
    unsigned char* eaw = (unsigned char*)carve((size_t)NE * 128);
    int* rowptr    = (int*)carve((size_t)(NN + 1) * 4);
    int* cursor    = (int*)carve((size_t)NN * 4);
    int* hist      = (int*)carve((size_t)NN * 4);
    int* sexcl     = (int*)carve((size_t)NN * 4);
    int* bsum      = (int*)carve((size_t)256 * 4);
    u16* packed    = (u16*)carve((size_t)PACKN * 2);
    if (off > ws_size) {
        // sentinel: NaN output tells us the workspace was too small
        hipMemsetAsync(d_out, 0xFF, (size_t)out_size * 4, stream);
        return;
    }

    hipMemsetAsync(hist, 0, (size_t)NN * 4, stream);
    k_hist<<<(NE + 255) / 256, 256, 0, stream>>>(edst, hist);
    k_scanA<<<SCAN_B, 256, 0, stream>>>(hist, sexcl, bsum);
    k_scanB<<<1, 256, 0, stream>>>(bsum);
    k_scanC<<<SCAN_B, 256, 0, stream>>>(sexcl, bsum, rowptr, cursor);
    k_scatter<<<(NE + 255) / 256, 256, 0, stream>>>(esrc, edst, eattr, cursor, ssrc, ea8);
    k_eaw<<<EAW_BLOCKS, 256, 0, stream>>>(ea8, msg_w, eaw);
    k_pack<<<(PACKN + 255) / 256, 256, 0, stream>>>(up_w1, up_w2, msg_w, enc_w, packed);
    k_encode<<<(NN + 63) / 64, 256, 0, stream>>>(x, enc_b, msg_b, packed, state_f, state_h, swb);
    for (int t = 0; t < T_STEPS; ++t) {
        k_edge<<<(NN + 7) / 8, 256, 0, stream>>>(rowptr, ssrc, eaw, swb, aggb);
        k_update<<<(NN + 127) / 128, 256, 0, stream>>>(up_b1, up_b2, msg_b, packed, aggb,
                                                       state_f, state_h, swb);
    }
    k_logits<<<NB, 256, 0, stream>>>(state_f, batch, (float*)d_out);
}